// Round 6
// baseline (433.298 us; speedup 1.0000x reference)
//
#include <hip/hip_runtime.h>
#include <cstddef>
#include <cstdint>

#define CH 128     // IN_CH == HID_CH == 128
#define NBKT 196   // dst >> 9 -> buckets 0..195 (512 nodes each)
#define ABLK 320   // phase-A blocks
#define BKT_NODES 512

typedef __attribute__((ext_vector_type(8))) short short8;
typedef __attribute__((ext_vector_type(4))) float f32x4;
typedef __attribute__((ext_vector_type(2))) float f32x2;

__device__ __forceinline__ unsigned short f2bf(float f) {
  unsigned u = __float_as_uint(f);
  u += 0x7FFF + ((u >> 16) & 1);   // round-to-nearest-even
  return (unsigned short)(u >> 16);
}
__device__ __forceinline__ void gld16(const void* g, void* l) {
  __builtin_amdgcn_global_load_lds((const __attribute__((address_space(1))) unsigned int*)g,
                                   (__attribute__((address_space(3))) unsigned int*)l, 16, 0, 0);
}
// pack 4 fp32 -> 4 fp8 e4m3 (OCP on gfx950)
__device__ __forceinline__ unsigned int pk_fp8x4(float a, float b, float c, float d) {
  int p = __builtin_amdgcn_cvt_pk_fp8_f32(a, b, 0, false);
  p = __builtin_amdgcn_cvt_pk_fp8_f32(c, d, p, true);
  return (unsigned int)p;
}

// ============================ prep: weights + bin-hist + x convert, one dispatch ============================
// blocks [0,5): W^T bf16; [5,325): dst-bucket histogram; [325, 325+6250): x -> bf16 + fp8
__global__ __launch_bounds__(256)
void k_prep(const float* __restrict__ w0, const float* __restrict__ w1,
            const float* __restrict__ w2, const float* __restrict__ w3,
            const float* __restrict__ w4, unsigned short* __restrict__ wt,
            const int* __restrict__ dst, int* __restrict__ cnt, int E, int chunk,
            const float4* __restrict__ x4, uint4* __restrict__ xb,
            uint2* __restrict__ xb8, int n8) {
  __shared__ int c[NBKT];
  int b = blockIdx.x, t = threadIdx.x;
  if (b < 5) {
    const float* srcs[5] = {w0, w1, w2, w3, w4};
    const float* w = srcs[b];
    unsigned short* d = wt + (size_t)b * CH * CH;
    for (int idx = t; idx < CH * CH; idx += 256) {
      int k = idx >> 7, nn = idx & 127;
      d[nn * CH + k] = f2bf(w[idx]);
    }
  } else if (b < 5 + ABLK) {
    int ab = b - 5;
    for (int i = t; i < NBKT; i += 256) c[i] = 0;
    __syncthreads();
    int s = ab * chunk;
    int e = min(s + chunk, E);
    for (int i = s + t; i < e; i += 256)
      atomicAdd(&c[dst[i] >> 9], 1);
    __syncthreads();
    for (int i = t; i < NBKT; i += 256)
      cnt[i * ABLK + ab] = c[i];
  } else {
    int i = (b - 5 - ABLK) * 256 + t;
    if (i < n8) {
      float4 a = x4[i * 2], bb = x4[i * 2 + 1];
      uint4 o;
      o.x = (unsigned)f2bf(a.x) | ((unsigned)f2bf(a.y) << 16);
      o.y = (unsigned)f2bf(a.z) | ((unsigned)f2bf(a.w) << 16);
      o.z = (unsigned)f2bf(bb.x) | ((unsigned)f2bf(bb.y) << 16);
      o.w = (unsigned)f2bf(bb.z) | ((unsigned)f2bf(bb.w) << 16);
      xb[i] = o;
      uint2 o8;
      o8.x = pk_fp8x4(a.x, a.y, a.z, a.w);
      o8.y = pk_fp8x4(bb.x, bb.y, bb.z, bb.w);
      xb8[i] = o8;
    }
  }
}

// ============================ single-block scan of ofs (62720 elems, 16 tiles of 4096) ============================
__global__ __launch_bounds__(1024)
void k_scanA(int* __restrict__ arr, int n, int total) {
  __shared__ int sh[1024];
  int t = threadIdx.x;
  int run = 0;
  int tiles = (n + 4095) >> 12;
  for (int tt = 0; tt < tiles; tt++) {
    int base = (tt << 12) + t * 4;
    int v0 = (base + 0 < n) ? arr[base + 0] : 0;
    int v1 = (base + 1 < n) ? arr[base + 1] : 0;
    int v2 = (base + 2 < n) ? arr[base + 2] : 0;
    int v3 = (base + 3 < n) ? arr[base + 3] : 0;
    int tot = v0 + v1 + v2 + v3;
    sh[t] = tot;
    __syncthreads();
    for (int o = 1; o < 1024; o <<= 1) {
      int y = (t >= o) ? sh[t - o] : 0;
      __syncthreads();
      sh[t] += y;
      __syncthreads();
    }
    int excl = sh[t] - tot + run;
    int tile_total = sh[1023];
    if (base + 0 < n) arr[base + 0] = excl;
    if (base + 1 < n) arr[base + 1] = excl + v0;
    if (base + 2 < n) arr[base + 2] = excl + v0 + v1;
    if (base + 3 < n) arr[base + 3] = excl + v0 + v1 + v2;
    run += tile_total;
    __syncthreads();
  }
  if (t == 0) arr[n] = total;
}

// ============================ bin by dst>>9 (LDS cursors) ============================
// record = src (17b) | dst_local (9b) << 17
__global__ void k_bin(const int* __restrict__ src, const int* __restrict__ dst,
                      const int* __restrict__ ofs, unsigned int* __restrict__ binned,
                      int E, int chunk) {
  __shared__ int cur[NBKT];
  for (int i = threadIdx.x; i < NBKT; i += 256) cur[i] = ofs[i * ABLK + blockIdx.x];
  __syncthreads();
  int s = blockIdx.x * chunk;
  int e = min(s + chunk, E);
  for (int i = s + threadIdx.x; i < e; i += 256) {
    int d = dst[i];
    int b = d >> 9;
    int pos = atomicAdd(&cur[b], 1);   // LDS atomic
    binned[pos] = (unsigned)src[i] | ((unsigned)(d & 511) << 17);
  }
}

// ============================ per-bucket: hist + scan + rowptr + scatter ============================
__global__ __launch_bounds__(256)
void k_bucket(const unsigned int* __restrict__ binned, const int* __restrict__ ofs,
              int* __restrict__ rowptr, int* __restrict__ sorted, int N, int E, int nbkt) {
  __shared__ int c[BKT_NODES];
  __shared__ int tsum[256];
  __shared__ int cur[BKT_NODES];
  int b = blockIdx.x, t = threadIdx.x;
  int s = ofs[b * ABLK];
  int e = ofs[(b + 1) * ABLK];   // last bucket: ofs[NBKT*ABLK] == E
  c[t] = 0; c[t + 256] = 0;
  __syncthreads();
  for (int i = s + t; i < e; i += 256)
    atomicAdd(&c[binned[i] >> 17], 1);
  __syncthreads();
  int v0 = c[2 * t], v1 = c[2 * t + 1];
  int tot = v0 + v1;
  tsum[t] = tot;
  __syncthreads();
  for (int o = 1; o < 256; o <<= 1) {
    int y = (t >= o) ? tsum[t - o] : 0;
    __syncthreads();
    tsum[t] += y;
    __syncthreads();
  }
  int excl = tsum[t] - tot;
  int base = b * BKT_NODES;
  int r0 = s + excl, r1 = s + excl + v0;
  if (base + 2 * t < N)     rowptr[base + 2 * t]     = r0;
  if (base + 2 * t + 1 < N) rowptr[base + 2 * t + 1] = r1;
  cur[2 * t] = r0; cur[2 * t + 1] = r1;
  __syncthreads();
  for (int i = s + t; i < e; i += 256) {
    unsigned w = binned[i];
    int pos = atomicAdd(&cur[w >> 17], 1);   // LDS atomic
    sorted[pos] = w & 0x1FFFF;
  }
  if (b == nbkt - 1 && t == 0) rowptr[N] = E;
}

// ============================ mean aggregation v4: fp8 gather ============================
// Row = 128 B fp8 (2 cache lines vs 4 for bf16). Half-waves process edge pairs;
// lane holds uint (4 fp8 channels), 32 lanes per row. fp32 accumulate, bf16 mean out.
__global__ __launch_bounds__(256)
void k_agg8(const unsigned int* __restrict__ in8, uint2* __restrict__ outb,
            const int* __restrict__ rowptr, const int* __restrict__ sorted_src,
            int n, int nwaves) {
  int wid = (blockIdx.x * 256 + threadIdx.x) >> 6;
  int lane = threadIdx.x & 63;
  int half = lane >> 5;        // 0: even edges, 1: odd edges
  int sl = lane & 31;          // uint index within 128B fp8 row

  for (int node = wid; node < n; node += nwaves) {
    int beg = rowptr[node], end = rowptr[node + 1];
    float a0 = 0.f, a1 = 0.f, a2 = 0.f, a3 = 0.f;
    int e = beg;
    for (; e + 8 <= end; e += 8) {       // 4 pair-iterations = 8 edges
      unsigned int v[4];
#pragma unroll
      for (int j = 0; j < 4; j++)
        v[j] = in8[((unsigned)sorted_src[e + 2 * j + half] << 5) + sl];
#pragma unroll
      for (int j = 0; j < 4; j++) {
        f32x2 lo = __builtin_amdgcn_cvt_pk_f32_fp8(v[j], false);
        f32x2 hi = __builtin_amdgcn_cvt_pk_f32_fp8(v[j], true);
        a0 += lo.x; a1 += lo.y; a2 += hi.x; a3 += hi.y;
      }
    }
    if (e < end) {                        // masked tail (value-predicated)
      unsigned int v[4];
#pragma unroll
      for (int j = 0; j < 4; j++) {
        int k = e + 2 * j + half;
        int idx = (k < end) ? k : beg;    // clamped loads hit L1 (row[beg] hot)
        unsigned int tv = in8[((unsigned)sorted_src[idx] << 5) + sl];
        v[j] = (k < end) ? tv : 0u;       // fp8 0x00 == 0.0
      }
#pragma unroll
      for (int j = 0; j < 4; j++) {
        f32x2 lo = __builtin_amdgcn_cvt_pk_f32_fp8(v[j], false);
        f32x2 hi = __builtin_amdgcn_cvt_pk_f32_fp8(v[j], true);
        a0 += lo.x; a1 += lo.y; a2 += hi.x; a3 += hi.y;
      }
    }
    a0 += __shfl(a0, lane ^ 32);
    a1 += __shfl(a1, lane ^ 32);
    a2 += __shfl(a2, lane ^ 32);
    a3 += __shfl(a3, lane ^ 32);
    int d = end - beg;
    float inv = (d > 0) ? (1.f / (float)d) : 0.f;
    if (half == 0) {
      uint2 o;
      o.x = (unsigned)f2bf(a0 * inv) | ((unsigned)f2bf(a1 * inv) << 16);
      o.y = (unsigned)f2bf(a2 * inv) | ((unsigned)f2bf(a3 * inv) << 16);
      outb[((unsigned)node << 5) + sl] = o;
    }
  }
}

// ============================ fused SAGE dual-GEMM via MFMA bf16 ============================
// out = relu(Am@Wl + bias + Ax@Wr); optionally also writes fp8 mirror (out8) for next agg.
__global__ __launch_bounds__(256, 2)
void k_sage(const unsigned short* __restrict__ Am, const unsigned short* __restrict__ Ax,
            const unsigned short* __restrict__ WTl, const unsigned short* __restrict__ WTr,
            const float* __restrict__ bias, unsigned short* __restrict__ out,
            unsigned char* __restrict__ out8, int n) {
  __shared__ unsigned short sA[128 * 64];
  __shared__ unsigned short sB[128 * 64];
  int tid = threadIdx.x;
  int lane = tid & 63;
  int w = tid >> 6;
  int row0 = blockIdx.x * 128;
  int col_lo = lane & 15, quad = lane >> 4;

  f32x4 acc[2][8];
#pragma unroll
  for (int mt = 0; mt < 2; mt++)
#pragma unroll
    for (int nt = 0; nt < 8; nt++) acc[mt][nt] = (f32x4){0.f, 0.f, 0.f, 0.f};

  const unsigned short* As[4] = {Am, Am, Ax, Ax};
  const unsigned short* Bs[4] = {WTl, WTl, WTr, WTr};
  const int k0s[4] = {0, 64, 0, 64};

  for (int c = 0; c < 4; c++) {
    const unsigned short* Ap = As[c];
    const unsigned short* Bp = Bs[c];
    int k0 = k0s[c];
#pragma unroll
    for (int it = 0; it < 4; it++) {
      int flat = it * 256 + tid;
      int r = flat >> 3;
      int kof = (flat & 7) * 8;
      int gr = row0 + r;
      if (gr > n - 1) gr = n - 1;
      gld16(Ap + (size_t)gr * CH + k0 + kof, sA + flat * 8);
      gld16(Bp + (size_t)r * CH + k0 + kof, sB + flat * 8);
    }
    __syncthreads();

#pragma unroll
    for (int ks = 0; ks < 2; ks++) {
      short8 a0 = *(const short8*)&sA[(w * 32 + col_lo) * 64 + ks * 32 + quad * 8];
      short8 a1 = *(const short8*)&sA[(w * 32 + 16 + col_lo) * 64 + ks * 32 + quad * 8];
      short8 b[8];
#pragma unroll
      for (int nt = 0; nt < 8; nt++)
        b[nt] = *(const short8*)&sB[(nt * 16 + col_lo) * 64 + ks * 32 + quad * 8];
#pragma unroll
      for (int nt = 0; nt < 8; nt++) {
        acc[0][nt] = __builtin_amdgcn_mfma_f32_16x16x32_bf16(a0, b[nt], acc[0][nt], 0, 0, 0);
        acc[1][nt] = __builtin_amdgcn_mfma_f32_16x16x32_bf16(a1, b[nt], acc[1][nt], 0, 0, 0);
      }
    }
    __syncthreads();
  }

#pragma unroll
  for (int nt = 0; nt < 8; nt++) {
    float bb = bias[nt * 16 + col_lo];
#pragma unroll
    for (int mt = 0; mt < 2; mt++) {
#pragma unroll
      for (int r = 0; r < 4; r++) {
        int rr = row0 + w * 32 + mt * 16 + quad * 4 + r;
        if (rr < n) {
          int cc = nt * 16 + col_lo;
          float v = fmaxf(acc[mt][nt][r] + bb, 0.f);
          out[(size_t)rr * CH + cc] = f2bf(v);
          if (out8) {
            int p = __builtin_amdgcn_cvt_pk_fp8_f32(v, v, 0, false);
            out8[(size_t)rr * CH + cc] = (unsigned char)(p & 0xff);
          }
        }
      }
    }
  }
}

// ============================ decoder GEMM via MFMA ============================
__global__ __launch_bounds__(256, 2)
void k_dec(const unsigned short* __restrict__ H, const unsigned short* __restrict__ WTd,
           const float* __restrict__ bd, const float* __restrict__ X,
           const float* __restrict__ alpha_p, float* __restrict__ out, int n) {
  __shared__ unsigned short sA[128 * 64];
  __shared__ unsigned short sB[128 * 64];
  int tid = threadIdx.x;
  int lane = tid & 63;
  int w = tid >> 6;
  int row0 = blockIdx.x * 128;
  int col_lo = lane & 15, quad = lane >> 4;

  f32x4 acc[2][8];
#pragma unroll
  for (int mt = 0; mt < 2; mt++)
#pragma unroll
    for (int nt = 0; nt < 8; nt++) acc[mt][nt] = (f32x4){0.f, 0.f, 0.f, 0.f};

  for (int c = 0; c < 2; c++) {
    int k0 = c * 64;
#pragma unroll
    for (int it = 0; it < 4; it++) {
      int flat = it * 256 + tid;
      int r = flat >> 3;
      int kof = (flat & 7) * 8;
      int gr = row0 + r;
      if (gr > n - 1) gr = n - 1;
      gld16(H + (size_t)gr * CH + k0 + kof, sA + flat * 8);
      gld16(WTd + (size_t)r * CH + k0 + kof, sB + flat * 8);
    }
    __syncthreads();

#pragma unroll
    for (int ks = 0; ks < 2; ks++) {
      short8 a0 = *(const short8*)&sA[(w * 32 + col_lo) * 64 + ks * 32 + quad * 8];
      short8 a1 = *(const short8*)&sA[(w * 32 + 16 + col_lo) * 64 + ks * 32 + quad * 8];
      short8 b[8];
#pragma unroll
      for (int nt = 0; nt < 8; nt++)
        b[nt] = *(const short8*)&sB[(nt * 16 + col_lo) * 64 + ks * 32 + quad * 8];
#pragma unroll
      for (int nt = 0; nt < 8; nt++) {
        acc[0][nt] = __builtin_amdgcn_mfma_f32_16x16x32_bf16(a0, b[nt], acc[0][nt], 0, 0, 0);
        acc[1][nt] = __builtin_amdgcn_mfma_f32_16x16x32_bf16(a1, b[nt], acc[1][nt], 0, 0, 0);
      }
    }
    __syncthreads();
  }

  float al = alpha_p[0];
  float be = 1.f - al;
#pragma unroll
  for (int nt = 0; nt < 8; nt++) {
    float bb = bd[nt * 16 + col_lo];
#pragma unroll
    for (int mt = 0; mt < 2; mt++) {
#pragma unroll
      for (int r = 0; r < 4; r++) {
        int rr = row0 + w * 32 + mt * 16 + quad * 4 + r;
        if (rr < n) {
          int cc = nt * 16 + col_lo;
          float xv = X[(size_t)rr * CH + cc];
          out[(size_t)rr * CH + cc] = al * (acc[mt][nt][r] + bb) + be * xv;
        }
      }
    }
  }
}

// ============================ launch ============================

extern "C" void kernel_launch(void* const* d_in, const int* in_sizes, int n_in,
                              void* d_out, int out_size, void* d_ws, size_t ws_size,
                              hipStream_t stream) {
  const float* x   = (const float*)d_in[0];
  const int*   ei  = (const int*)d_in[1];
  const float* W1l = (const float*)d_in[2];
  const float* b1  = (const float*)d_in[3];
  const float* W1r = (const float*)d_in[4];
  const float* W2l = (const float*)d_in[5];
  const float* b2  = (const float*)d_in[6];
  const float* W2r = (const float*)d_in[7];
  const float* Wd  = (const float*)d_in[8];
  const float* bd  = (const float*)d_in[9];
  const float* alp = (const float*)d_in[10];

  int N = in_sizes[0] / CH;   // 100000
  int E = in_sizes[1] / 2;    // 1600000
  const int* src = ei;
  const int* dst = ei + E;

  char* ws = (char*)d_ws;
  size_t off = 0;
  auto alloc = [&](size_t bytes) -> char* {
    off = (off + 511) & ~size_t(511);
    char* p = ws + off;
    off += bytes;
    return p;
  };
  int*   rowptr = (int*)alloc((size_t)(N + 1) * 4);
  int*   ofs    = (int*)alloc((size_t)(NBKT * ABLK + 1) * 4);
  int*   sorted = (int*)alloc((size_t)E * 4);
  unsigned short* xb = (unsigned short*)alloc((size_t)N * CH * 2);
  unsigned short* h  = (unsigned short*)alloc((size_t)N * CH * 2);
  unsigned short* WT = (unsigned short*)alloc((size_t)5 * CH * CH * 2);

  // d_out (51.2 MB) layout during the pipeline (k_dec fully overwrites at the end):
  //   [0, 25.6 MB):    bf16 mean scratch
  //   [25.6, 38.4 MB): xb8  - fp8 mirror of x   (written by k_prep, read by agg L1)
  //   [38.4, 51.2 MB): binned (6.4 MB, dead after k_bucket) then h8 (fp8 mirror of h1)
  unsigned short* mean  = (unsigned short*)d_out;
  unsigned char* xb8    = (unsigned char*)d_out + (size_t)N * CH * 2;
  char*          upper  = (char*)d_out + (size_t)N * CH * 3;
  unsigned int* binned  = (unsigned int*)upper;
  unsigned char* h8     = (unsigned char*)upper;

  int chunk = (E + ABLK - 1) / ABLK;   // 5000
  int nA = NBKT * ABLK;                // 62720
  int n8 = N * CH / 8;                 // 1.6M
  int gCvt = (n8 + 255) / 256;         // 6250

  // 1) prep: weights + bucket hist + x convert (bf16 + fp8)
  k_prep<<<5 + ABLK + gCvt, 256, 0, stream>>>(W1l, W1r, W2l, W2r, Wd, WT,
                                              dst, ofs, E, chunk,
                                              (const float4*)x, (uint4*)xb,
                                              (uint2*)xb8, n8);
  // 2) scan of per-(bucket,block) counts
  k_scanA<<<1, 1024, 0, stream>>>(ofs, nA, E);
  // 3) bin edges into bucket runs
  k_bin<<<ABLK, 256, 0, stream>>>(src, dst, ofs, binned, E, chunk);
  // 4) per-bucket: rowptr + dst-sorted src
  k_bucket<<<NBKT, 256, 0, stream>>>(binned, ofs, rowptr, sorted, N, E, NBKT);

  int gAggBlocks = 2048;               // 8192 waves, ~12 nodes/wave
  int nWaves = gAggBlocks * 4;
  int gGemm = (N + 127) / 128;
  unsigned short* WT1l = WT + 0 * CH * CH;
  unsigned short* WT1r = WT + 1 * CH * CH;
  unsigned short* WT2l = WT + 2 * CH * CH;
  unsigned short* WT2r = WT + 3 * CH * CH;
  unsigned short* WTd  = WT + 4 * CH * CH;

  // 5) layer 1 aggregate (fp8 gather) ; 6) sage1 writes h bf16 + h8 fp8 (overwrites dead binned)
  k_agg8<<<gAggBlocks, 256, 0, stream>>>((const unsigned int*)xb8, (uint2*)mean,
                                         rowptr, sorted, N, nWaves);
  k_sage<<<gGemm, 256, 0, stream>>>(mean, xb, WT1l, WT1r, b1, h, h8, N);
  // 7) layer 2 aggregate ; 8) sage2 (no fp8 mirror needed)
  k_agg8<<<gAggBlocks, 256, 0, stream>>>((const unsigned int*)h8, (uint2*)mean,
                                         rowptr, sorted, N, nWaves);
  k_sage<<<gGemm, 256, 0, stream>>>(mean, h, WT2l, WT2r, b2, h, (unsigned char*)nullptr, N);
  // 9) decoder
  k_dec<<<gGemm, 256, 0, stream>>>(h, WTd, bd, x, alp, (float*)d_out, N);
}